// Round 8
// baseline (2507.903 us; speedup 1.0000x reference)
//
#include <hip/hip_runtime.h>

// LJ 12-6 over a neighbor list — round 8: split filter/compact + gather/compute.
// (R7 resubmit; fix: __builtin_nontemporal_store can't take struct int2 —
// use ext_vector v2i.)
// R6 fused kernel (91.5 us) was sum-of-pipes: 150KB LDS table -> 1 WG/CU ->
// 16 waves with a serial idx->filter->gather chain. Split:
//   A: LDS cell filter + wave-ballot compaction of survivors (24.4%) -> 25 MB
//   B: high-occupancy gather+LJ over the compacted list (line-request bound)

typedef int   v2i __attribute__((ext_vector_type(2)));
typedef int   v4i __attribute__((ext_vector_type(4)));
typedef float v4f __attribute__((ext_vector_type(4)));

#define CELL_SZ   15.0f
#define INV_CELL  (1.0f / 15.0f)
#define GRP       8
#define WGT       1024
#define NWG_A     1024
#define NWG_B     2048

__global__ void __launch_bounds__(256) pad_R_kernel(
    const float* __restrict__ R, v4f* __restrict__ Rp, int n_atoms)
{
    int a = blockIdx.x * blockDim.x + threadIdx.x;
    if (a < n_atoms) {
        v4f v;
        v.x = R[3 * a + 0];
        v.y = R[3 * a + 1];
        v.z = R[3 * a + 2];
        v.w = 0.0f;
        Rp[a] = v;  // 16B aligned: single-transaction gathers
    }
}

// Pack 6-bit cell ids: thread t owns atoms [16t,16t+16) -> 96 bits -> 3 words.
__global__ void __launch_bounds__(256) cell_kernel(
    const float* __restrict__ R, unsigned* __restrict__ packed, int n_atoms)
{
    int t = blockIdx.x * blockDim.x + threadIdx.x;
    int n_thr = (n_atoms + 15) >> 4;
    if (t >= n_thr) return;
    int a0 = t << 4;
    unsigned w[3] = {0u, 0u, 0u};
#pragma unroll
    for (int k = 0; k < 16; ++k) {
        int a = a0 + k;
        unsigned c = 0u;
        if (a < n_atoms) {
            int cx = min(3, max(0, (int)(R[3 * a + 0] * INV_CELL)));
            int cy = min(3, max(0, (int)(R[3 * a + 1] * INV_CELL)));
            int cz = min(3, max(0, (int)(R[3 * a + 2] * INV_CELL)));
            c = (unsigned)(cx | (cy << 2) | (cz << 4));
        }
        int bit = 6 * k, word = bit >> 5, off = bit & 31;
        w[word] |= c << off;
        if (off > 26) w[word + 1] |= c >> (32 - off);
    }
    packed[3 * t + 0] = w[0];
    packed[3 * t + 1] = w[1];
    packed[3 * t + 2] = w[2];
}

__device__ __forceinline__ unsigned cell6(const unsigned char* c8, unsigned a) {
    unsigned bit = a * 6u;
    unsigned by  = bit >> 3;
    unsigned v   = (unsigned)c8[by] | ((unsigned)c8[by + 1] << 8);
    return (v >> (bit & 7u)) & 63u;
}

__device__ __forceinline__ void lj_body(
    v4f A, v4f B, float eps, float s2, float cut2, int gi,
    float* __restrict__ energy, float* __restrict__ forces)
{
    const float dx = A.x - B.x, dy = A.y - B.y, dz = A.z - B.z;
    const float r2 = dx * dx + dy * dy + dz * dz;
    if (r2 < cut2 && r2 > 1e-10f) {
        const float inv  = 1.0f / r2;
        const float sr2  = s2 * inv;
        const float sr6  = sr2 * sr2 * sr2;
        const float sr12 = sr6 * sr6;
        const float e    = 2.0f * eps * (sr12 - sr6);              // 0.5 * 4eps
        const float f    = 24.0f * eps * (2.0f * sr12 - sr6) * inv;
        atomicAdd(&energy[gi], e);
        atomicAdd(&forces[3 * gi + 0], f * dx);
        atomicAdd(&forces[3 * gi + 1], f * dy);
        atomicAdd(&forces[3 * gi + 2], f * dz);
    }
}

// Kernel A: cell filter + wave-ballot compaction. No gathers (short chain).
__global__ void __launch_bounds__(WGT) filter_compact_kernel(
    const v4f* __restrict__ Rp,            // only for rare overflow path
    const unsigned* __restrict__ packed,
    const int* __restrict__ idx_i,
    const int* __restrict__ idx_j,
    const float* __restrict__ eps_p,
    const float* __restrict__ sig_p,
    const float* __restrict__ cut_p,
    v2i* __restrict__ out_list,
    unsigned* __restrict__ cursor,         // cursor[0] = survivor count
    float* __restrict__ energy,
    float* __restrict__ forces,
    int n_pairs, int pk_words, int chunk, unsigned cap)
{
    extern __shared__ unsigned lds[];
    for (int w = threadIdx.x; w < pk_words; w += WGT)
        lds[w] = packed[w];
    __syncthreads();
    const unsigned char* c8 = (const unsigned char*)lds;

    const float eps  = eps_p[0];
    const float sig  = sig_p[0];
    const float cut  = cut_p[0];
    const float s2   = sig * sig;
    const float cut2 = cut * cut;
    const bool nofilter = (cut2 > CELL_SZ * CELL_SZ);
    const int  lane = threadIdx.x & 63;

    const int cs = blockIdx.x * chunk;
    const int ce = min(cs + chunk, n_pairs);

    for (int p = cs + threadIdx.x * GRP; p < ce; p += WGT * GRP) {
        int is8[GRP], js8[GRP];
        bool valid[GRP];
        if (p + GRP <= n_pairs) {   // p % 8 == 0 -> int4-aligned
            v4i a0 = __builtin_nontemporal_load((const v4i*)idx_i + (p >> 2));
            v4i a1 = __builtin_nontemporal_load((const v4i*)idx_i + (p >> 2) + 1);
            v4i b0 = __builtin_nontemporal_load((const v4i*)idx_j + (p >> 2));
            v4i b1 = __builtin_nontemporal_load((const v4i*)idx_j + (p >> 2) + 1);
            is8[0] = a0.x; is8[1] = a0.y; is8[2] = a0.z; is8[3] = a0.w;
            is8[4] = a1.x; is8[5] = a1.y; is8[6] = a1.z; is8[7] = a1.w;
            js8[0] = b0.x; js8[1] = b0.y; js8[2] = b0.z; js8[3] = b0.w;
            js8[4] = b1.x; js8[5] = b1.y; js8[6] = b1.z; js8[7] = b1.w;
#pragma unroll
            for (int k = 0; k < GRP; ++k) valid[k] = true;
        } else {
            for (int k = 0; k < GRP; ++k) {
                valid[k] = (p + k < n_pairs);
                is8[k] = valid[k] ? idx_i[p + k] : 0;
                js8[k] = valid[k] ? idx_j[p + k] : 0;
            }
        }

#pragma unroll
        for (int k = 0; k < GRP; ++k) {
            unsigned ci = cell6(c8, (unsigned)is8[k]);
            unsigned cj = cell6(c8, (unsigned)js8[k]);
            int ddx = (int)(ci & 3u)        - (int)(cj & 3u);
            int ddy = (int)((ci >> 2) & 3u) - (int)((cj >> 2) & 3u);
            int ddz = (int)(ci >> 4)        - (int)(cj >> 4);
            bool ok = ((unsigned)(ddx + 1) <= 2u) & ((unsigned)(ddy + 1) <= 2u)
                    & ((unsigned)(ddz + 1) <= 2u);
            bool pass = (ok | nofilter) & valid[k];

            unsigned long long bal = __ballot(pass);
            if (bal) {
                int cnt = __popcll(bal);
                unsigned base = 0;
                if (lane == 0) base = atomicAdd(cursor, (unsigned)cnt);
                base = (unsigned)__shfl((int)base, 0);
                if (pass) {
                    unsigned off  = (unsigned)__popcll(bal & ((1ull << lane) - 1ull));
                    unsigned slot = base + off;
                    if (slot < cap) {
                        v2i pr;
                        pr.x = is8[k];
                        pr.y = js8[k];
                        __builtin_nontemporal_store(pr, &out_list[slot]);
                    } else {
                        // overflow (ws too small for survivor count): compute now
                        lj_body(Rp[is8[k]], Rp[js8[k]], eps, s2, cut2,
                                is8[k], energy, forces);
                    }
                }
            }
        }
    }
}

// Kernel B: gathers + LJ over the compacted list. No LDS -> 32 waves/CU.
__global__ void __launch_bounds__(256) lj_compact_kernel(
    const v4f* __restrict__ Rp,
    const v2i* __restrict__ list,
    const unsigned* __restrict__ cursor,
    const float* __restrict__ eps_p,
    const float* __restrict__ sig_p,
    const float* __restrict__ cut_p,
    float* __restrict__ energy,
    float* __restrict__ forces,
    unsigned cap)
{
    unsigned n = *cursor;
    if (n > cap) n = cap;

    const float eps  = eps_p[0];
    const float sig  = sig_p[0];
    const float cut  = cut_p[0];
    const float s2   = sig * sig;
    const float cut2 = cut * cut;

    const unsigned stride = gridDim.x * blockDim.x;
    unsigned t = blockIdx.x * blockDim.x + threadIdx.x;

    // 4 pairs per iter: list is 8B-aligned v2i; 4-entry groups are 32B.
    for (unsigned p0 = t * 4u; p0 < n; p0 += stride * 4u) {
        if (p0 + 4u <= n) {
            v4i w0 = __builtin_nontemporal_load((const v4i*)(list + p0));
            v4i w1 = __builtin_nontemporal_load((const v4i*)(list + p0) + 1);
            int is4[4] = { w0.x, w0.z, w1.x, w1.z };
            int js4[4] = { w0.y, w0.w, w1.y, w1.w };
            v4f A[4], B[4];
#pragma unroll
            for (int k = 0; k < 4; ++k) A[k] = Rp[is4[k]];
#pragma unroll
            for (int k = 0; k < 4; ++k) B[k] = Rp[js4[k]];
#pragma unroll
            for (int k = 0; k < 4; ++k)
                lj_body(A[k], B[k], eps, s2, cut2, is4[k], energy, forces);
        } else {
            for (unsigned p = p0; p < n; ++p) {
                v2i ij = list[p];
                lj_body(Rp[ij.x], Rp[ij.y], eps, s2, cut2, ij.x, energy, forces);
            }
        }
    }
}

// ---------- fallback (R2 structure, 131 us) if ws insufficient ----------
#define PPT 8
__global__ void __launch_bounds__(256) lj_pairs_fb_kernel(
    const v4f* __restrict__ Rp,
    const v4i* __restrict__ idx_i4, const v4i* __restrict__ idx_j4,
    const float* __restrict__ eps_p, const float* __restrict__ sig_p,
    const float* __restrict__ cut_p,
    float* __restrict__ energy, float* __restrict__ forces, int n_oct)
{
    int t = blockIdx.x * blockDim.x + threadIdx.x;
    if (t >= n_oct) return;
    const float eps  = eps_p[0];
    const float sig  = sig_p[0];
    const float cut  = cut_p[0];
    const float s2   = sig * sig;
    const float cut2 = cut * cut;
    v4i ii0 = __builtin_nontemporal_load(idx_i4 + 2 * t);
    v4i ii1 = __builtin_nontemporal_load(idx_i4 + 2 * t + 1);
    v4i jj0 = __builtin_nontemporal_load(idx_j4 + 2 * t);
    v4i jj1 = __builtin_nontemporal_load(idx_j4 + 2 * t + 1);
    int is[PPT] = { ii0.x, ii0.y, ii0.z, ii0.w, ii1.x, ii1.y, ii1.z, ii1.w };
    int js[PPT] = { jj0.x, jj0.y, jj0.z, jj0.w, jj1.x, jj1.y, jj1.z, jj1.w };
    v4f Ri[PPT], Rj[PPT];
#pragma unroll
    for (int k = 0; k < PPT; ++k) Ri[k] = Rp[is[k]];
#pragma unroll
    for (int k = 0; k < PPT; ++k) Rj[k] = Rp[js[k]];
#pragma unroll
    for (int k = 0; k < PPT; ++k)
        lj_body(Ri[k], Rj[k], eps, s2, cut2, is[k], energy, forces);
}

__global__ void lj_pairs_fb_tail_kernel(
    const v4f* __restrict__ Rp,
    const int* __restrict__ idx_i, const int* __restrict__ idx_j,
    const float* __restrict__ eps_p, const float* __restrict__ sig_p,
    const float* __restrict__ cut_p,
    float* __restrict__ energy, float* __restrict__ forces,
    int start, int n_pairs)
{
    int p = start + blockIdx.x * blockDim.x + threadIdx.x;
    if (p >= n_pairs) return;
    const float eps = eps_p[0];
    const float sig = sig_p[0];
    const float cut = cut_p[0];
    lj_body(Rp[idx_i[p]], Rp[idx_j[p]], eps, sig * sig, cut * cut,
            idx_i[p], energy, forces);
}
// -----------------------------------------------------------------------

extern "C" void kernel_launch(void* const* d_in, const int* in_sizes, int n_in,
                              void* d_out, int out_size, void* d_ws, size_t ws_size,
                              hipStream_t stream) {
    const float* R     = (const float*)d_in[0];
    const float* eps_p = (const float*)d_in[1];
    const float* sig_p = (const float*)d_in[2];
    const float* cut_p = (const float*)d_in[3];
    const int*   idx_i = (const int*)d_in[4];
    const int*   idx_j = (const int*)d_in[5];

    const int n_atoms = in_sizes[0] / 3;
    const int n_pairs = in_sizes[4];

    float* energy = (float*)d_out;
    float* forces = (float*)d_out + n_atoms;

    // d_out re-poisoned 0xAA before every timed call — zero it.
    (void)hipMemsetAsync(d_out, 0, (size_t)out_size * sizeof(float), stream);

    // ws layout: [Rp float4][packed cell table][cursor 256B][compact list]
    char* ws = (char*)d_ws;
    const size_t rp_b     = (((size_t)n_atoms * 16) + 255) & ~(size_t)255;
    const int    n_thr    = (n_atoms + 15) >> 4;
    const int    pk_words = 3 * n_thr + 1;               // +1 word read pad
    const size_t pk_b     = (((size_t)pk_words * 4) + 255) & ~(size_t)255;
    const size_t lds_b    = (((size_t)pk_words * 4) + 15) & ~(size_t)15;
    const size_t cur_b    = 256;

    const bool have_rp = ws_size >= rp_b;
    size_t fixed = rp_b + pk_b + cur_b;
    unsigned cap = 0;
    if (ws_size > fixed) {
        size_t c = (ws_size - fixed) / 8;  // bytes per v2i
        cap = (c > 0xFFFFFFFFull) ? 0xFFFFFFFFu : (unsigned)c;
    }
    const bool use_filter = have_rp && (lds_b <= 160000) && (cap >= 1u << 20);

    v4f*      Rp     = (v4f*)ws;
    unsigned* packed = (unsigned*)(ws + rp_b);
    unsigned* cursor = (unsigned*)(ws + rp_b + pk_b);
    v2i*      list   = (v2i*)(ws + fixed);

    if (have_rp) {
        int blocks = (n_atoms + 255) / 256;
        pad_R_kernel<<<blocks, 256, 0, stream>>>(R, Rp, n_atoms);
    }

    if (use_filter) {
        int cblocks = (n_thr + 255) / 256;
        cell_kernel<<<cblocks, 256, 0, stream>>>(R, packed, n_atoms);
        (void)hipMemsetAsync(cursor, 0, cur_b, stream);

        (void)hipFuncSetAttribute((const void*)filter_compact_kernel,
                                  hipFuncAttributeMaxDynamicSharedMemorySize,
                                  (int)lds_b);

        int chunk = (((n_pairs + NWG_A - 1) / NWG_A) + GRP - 1) & ~(GRP - 1);
        filter_compact_kernel<<<NWG_A, WGT, lds_b, stream>>>(
            Rp, packed, idx_i, idx_j, eps_p, sig_p, cut_p,
            list, cursor, energy, forces, n_pairs, pk_words, chunk, cap);

        lj_compact_kernel<<<NWG_B, 256, 0, stream>>>(
            Rp, list, cursor, eps_p, sig_p, cut_p, energy, forces, cap);
    } else {
        const int n_oct = n_pairs / PPT;
        const int start = n_oct * PPT;
        if (n_oct > 0) {
            int blocks = (n_oct + 255) / 256;
            lj_pairs_fb_kernel<<<blocks, 256, 0, stream>>>(
                Rp, (const v4i*)idx_i, (const v4i*)idx_j,
                eps_p, sig_p, cut_p, energy, forces, n_oct);
        }
        if (start < n_pairs) {
            lj_pairs_fb_tail_kernel<<<1, 64, 0, stream>>>(
                Rp, idx_i, idx_j, eps_p, sig_p, cut_p,
                energy, forces, start, n_pairs);
        }
    }
}

// Round 9
// 228.805 us; speedup vs baseline: 10.9609x; 10.9609x over previous
//
#include <hip/hip_runtime.h>

// LJ 12-6 over a neighbor list — round 9: split pipeline, hierarchical cursor.
// R8's scalar global cursor (262k same-address atomic-with-return, ~21 cyc
// serialized each) cost 2.3 ms. Fix: ballot -> LDS wave counts -> ONE global
// atomicAdd per WG per chunk-iteration (2048 total). Loop restructured to
// WG-uniform iteration count so __syncthreads() is legal inside.

typedef int   v2i __attribute__((ext_vector_type(2)));
typedef int   v4i __attribute__((ext_vector_type(4)));
typedef float v4f __attribute__((ext_vector_type(4)));

#define CELL_SZ   15.0f
#define INV_CELL  (1.0f / 15.0f)
#define GRP       8
#define WGT       1024
#define NWAVES    (WGT / 64)
#define NWG_A     1024
#define NWG_B     2048

__global__ void __launch_bounds__(256) pad_R_kernel(
    const float* __restrict__ R, v4f* __restrict__ Rp, int n_atoms)
{
    int a = blockIdx.x * blockDim.x + threadIdx.x;
    if (a < n_atoms) {
        v4f v;
        v.x = R[3 * a + 0];
        v.y = R[3 * a + 1];
        v.z = R[3 * a + 2];
        v.w = 0.0f;
        Rp[a] = v;  // 16B aligned: single-transaction gathers
    }
}

// Pack 6-bit cell ids: thread t owns atoms [16t,16t+16) -> 96 bits -> 3 words.
__global__ void __launch_bounds__(256) cell_kernel(
    const float* __restrict__ R, unsigned* __restrict__ packed, int n_atoms)
{
    int t = blockIdx.x * blockDim.x + threadIdx.x;
    int n_thr = (n_atoms + 15) >> 4;
    if (t >= n_thr) return;
    int a0 = t << 4;
    unsigned w[3] = {0u, 0u, 0u};
#pragma unroll
    for (int k = 0; k < 16; ++k) {
        int a = a0 + k;
        unsigned c = 0u;
        if (a < n_atoms) {
            int cx = min(3, max(0, (int)(R[3 * a + 0] * INV_CELL)));
            int cy = min(3, max(0, (int)(R[3 * a + 1] * INV_CELL)));
            int cz = min(3, max(0, (int)(R[3 * a + 2] * INV_CELL)));
            c = (unsigned)(cx | (cy << 2) | (cz << 4));
        }
        int bit = 6 * k, word = bit >> 5, off = bit & 31;
        w[word] |= c << off;
        if (off > 26) w[word + 1] |= c >> (32 - off);
    }
    packed[3 * t + 0] = w[0];
    packed[3 * t + 1] = w[1];
    packed[3 * t + 2] = w[2];
}

__device__ __forceinline__ unsigned cell6(const unsigned char* c8, unsigned a) {
    unsigned bit = a * 6u;
    unsigned by  = bit >> 3;
    unsigned v   = (unsigned)c8[by] | ((unsigned)c8[by + 1] << 8);
    return (v >> (bit & 7u)) & 63u;
}

__device__ __forceinline__ void lj_body(
    v4f A, v4f B, float eps, float s2, float cut2, int gi,
    float* __restrict__ energy, float* __restrict__ forces)
{
    const float dx = A.x - B.x, dy = A.y - B.y, dz = A.z - B.z;
    const float r2 = dx * dx + dy * dy + dz * dz;
    if (r2 < cut2 && r2 > 1e-10f) {
        const float inv  = 1.0f / r2;
        const float sr2  = s2 * inv;
        const float sr6  = sr2 * sr2 * sr2;
        const float sr12 = sr6 * sr6;
        const float e    = 2.0f * eps * (sr12 - sr6);              // 0.5 * 4eps
        const float f    = 24.0f * eps * (2.0f * sr12 - sr6) * inv;
        atomicAdd(&energy[gi], e);
        atomicAdd(&forces[3 * gi + 0], f * dx);
        atomicAdd(&forces[3 * gi + 1], f * dy);
        atomicAdd(&forces[3 * gi + 2], f * dz);
    }
}

// Kernel A: cell filter + hierarchical compaction (1 global atomic per WG/iter).
__global__ void __launch_bounds__(WGT) filter_compact_kernel(
    const v4f* __restrict__ Rp,            // only for rare overflow path
    const unsigned* __restrict__ packed,
    const int* __restrict__ idx_i,
    const int* __restrict__ idx_j,
    const float* __restrict__ eps_p,
    const float* __restrict__ sig_p,
    const float* __restrict__ cut_p,
    v2i* __restrict__ out_list,
    unsigned* __restrict__ cursor,         // cursor[0] = survivor count
    float* __restrict__ energy,
    float* __restrict__ forces,
    int n_pairs, int pk_words, int chunk, unsigned cap)
{
    extern __shared__ unsigned lds[];
    __shared__ unsigned wv_cnt[NWAVES];
    __shared__ unsigned wv_base[NWAVES];
    __shared__ unsigned wg_base_s;

    for (int w = threadIdx.x; w < pk_words; w += WGT)
        lds[w] = packed[w];
    __syncthreads();
    const unsigned char* c8 = (const unsigned char*)lds;

    const float eps  = eps_p[0];
    const float sig  = sig_p[0];
    const float cut  = cut_p[0];
    const float s2   = sig * sig;
    const float cut2 = cut * cut;
    const bool nofilter = (cut2 > CELL_SZ * CELL_SZ);
    const int  lane = threadIdx.x & 63;
    const int  wv   = threadIdx.x >> 6;
    const unsigned long long lt = (1ull << lane) - 1ull;

    const int cs = blockIdx.x * chunk;
    const int ce = min(cs + chunk, n_pairs);
    // WG-uniform iteration count: __syncthreads inside requires no divergence.
    const int iters = (chunk + WGT * GRP - 1) / (WGT * GRP);

    for (int it = 0; it < iters; ++it) {
        const int p = cs + it * (WGT * GRP) + threadIdx.x * GRP;

        int is8[GRP], js8[GRP];
        bool valid[GRP];
        if (p + GRP <= ce) {   // p % 8 == 0 -> int4-aligned fast path
            v4i a0 = __builtin_nontemporal_load((const v4i*)idx_i + (p >> 2));
            v4i a1 = __builtin_nontemporal_load((const v4i*)idx_i + (p >> 2) + 1);
            v4i b0 = __builtin_nontemporal_load((const v4i*)idx_j + (p >> 2));
            v4i b1 = __builtin_nontemporal_load((const v4i*)idx_j + (p >> 2) + 1);
            is8[0] = a0.x; is8[1] = a0.y; is8[2] = a0.z; is8[3] = a0.w;
            is8[4] = a1.x; is8[5] = a1.y; is8[6] = a1.z; is8[7] = a1.w;
            js8[0] = b0.x; js8[1] = b0.y; js8[2] = b0.z; js8[3] = b0.w;
            js8[4] = b1.x; js8[5] = b1.y; js8[6] = b1.z; js8[7] = b1.w;
#pragma unroll
            for (int k = 0; k < GRP; ++k) valid[k] = true;
        } else {
#pragma unroll
            for (int k = 0; k < GRP; ++k) {
                valid[k] = (p + k < ce);
                is8[k] = valid[k] ? idx_i[p + k] : 0;
                js8[k] = valid[k] ? idx_j[p + k] : 0;
            }
        }

        // Filter + per-k wave ballots (all lanes participate every k).
        unsigned m = 0u;
        unsigned long long bal[GRP];
        unsigned wave_total = 0u;
#pragma unroll
        for (int k = 0; k < GRP; ++k) {
            unsigned ci = cell6(c8, (unsigned)is8[k]);
            unsigned cj = cell6(c8, (unsigned)js8[k]);
            int ddx = (int)(ci & 3u)        - (int)(cj & 3u);
            int ddy = (int)((ci >> 2) & 3u) - (int)((cj >> 2) & 3u);
            int ddz = (int)(ci >> 4)        - (int)(cj >> 4);
            bool ok = ((unsigned)(ddx + 1) <= 2u) & ((unsigned)(ddy + 1) <= 2u)
                    & ((unsigned)(ddz + 1) <= 2u);
            bool pass = (ok | nofilter) & valid[k];
            if (pass) m |= (1u << k);
            bal[k] = __ballot(pass);
            wave_total += (unsigned)__popcll(bal[k]);
        }

        // WG-level reservation: one global atomic per WG per iteration.
        if (lane == 0) wv_cnt[wv] = wave_total;
        __syncthreads();
        if (threadIdx.x == 0) {
            unsigned run = 0;
#pragma unroll
            for (int w = 0; w < NWAVES; ++w) {
                wv_base[w] = run;
                run += wv_cnt[w];
            }
            wg_base_s = run ? atomicAdd(cursor, run) : 0u;
        }
        __syncthreads();
        const unsigned tbase = wg_base_s + wv_base[wv];

        // Write survivors (contiguous per WG -> dense full-line writes).
        unsigned run_k = 0u;
#pragma unroll
        for (int k = 0; k < GRP; ++k) {
            if (m & (1u << k)) {
                unsigned slot = tbase + run_k + (unsigned)__popcll(bal[k] & lt);
                if (slot < cap) {
                    v2i pr;
                    pr.x = is8[k];
                    pr.y = js8[k];
                    __builtin_nontemporal_store(pr, &out_list[slot]);
                } else {
                    // overflow (ws too small for survivor count): compute now
                    lj_body(Rp[is8[k]], Rp[js8[k]], eps, s2, cut2,
                            is8[k], energy, forces);
                }
            }
            run_k += (unsigned)__popcll(bal[k]);
        }
    }
}

// Kernel B: gathers + LJ over the compacted list. No LDS -> 32 waves/CU.
__global__ void __launch_bounds__(256) lj_compact_kernel(
    const v4f* __restrict__ Rp,
    const v2i* __restrict__ list,
    const unsigned* __restrict__ cursor,
    const float* __restrict__ eps_p,
    const float* __restrict__ sig_p,
    const float* __restrict__ cut_p,
    float* __restrict__ energy,
    float* __restrict__ forces,
    unsigned cap)
{
    unsigned n = *cursor;
    if (n > cap) n = cap;

    const float eps  = eps_p[0];
    const float sig  = sig_p[0];
    const float cut  = cut_p[0];
    const float s2   = sig * sig;
    const float cut2 = cut * cut;

    const unsigned stride = gridDim.x * blockDim.x;
    unsigned t = blockIdx.x * blockDim.x + threadIdx.x;

    // 4 pairs per iter: list is 8B-aligned v2i; 4-entry groups are 32B.
    for (unsigned p0 = t * 4u; p0 < n; p0 += stride * 4u) {
        if (p0 + 4u <= n) {
            v4i w0 = __builtin_nontemporal_load((const v4i*)(list + p0));
            v4i w1 = __builtin_nontemporal_load((const v4i*)(list + p0) + 1);
            int is4[4] = { w0.x, w0.z, w1.x, w1.z };
            int js4[4] = { w0.y, w0.w, w1.y, w1.w };
            v4f A[4], B[4];
#pragma unroll
            for (int k = 0; k < 4; ++k) A[k] = Rp[is4[k]];
#pragma unroll
            for (int k = 0; k < 4; ++k) B[k] = Rp[js4[k]];
#pragma unroll
            for (int k = 0; k < 4; ++k)
                lj_body(A[k], B[k], eps, s2, cut2, is4[k], energy, forces);
        } else {
            for (unsigned p = p0; p < n; ++p) {
                v2i ij = list[p];
                lj_body(Rp[ij.x], Rp[ij.y], eps, s2, cut2, ij.x, energy, forces);
            }
        }
    }
}

// ---------- fallback (R2 structure, 131 us) if ws insufficient ----------
#define PPT 8
__global__ void __launch_bounds__(256) lj_pairs_fb_kernel(
    const v4f* __restrict__ Rp,
    const v4i* __restrict__ idx_i4, const v4i* __restrict__ idx_j4,
    const float* __restrict__ eps_p, const float* __restrict__ sig_p,
    const float* __restrict__ cut_p,
    float* __restrict__ energy, float* __restrict__ forces, int n_oct)
{
    int t = blockIdx.x * blockDim.x + threadIdx.x;
    if (t >= n_oct) return;
    const float eps  = eps_p[0];
    const float sig  = sig_p[0];
    const float cut  = cut_p[0];
    const float s2   = sig * sig;
    const float cut2 = cut * cut;
    v4i ii0 = __builtin_nontemporal_load(idx_i4 + 2 * t);
    v4i ii1 = __builtin_nontemporal_load(idx_i4 + 2 * t + 1);
    v4i jj0 = __builtin_nontemporal_load(idx_j4 + 2 * t);
    v4i jj1 = __builtin_nontemporal_load(idx_j4 + 2 * t + 1);
    int is[PPT] = { ii0.x, ii0.y, ii0.z, ii0.w, ii1.x, ii1.y, ii1.z, ii1.w };
    int js[PPT] = { jj0.x, jj0.y, jj0.z, jj0.w, jj1.x, jj1.y, jj1.z, jj1.w };
    v4f Ri[PPT], Rj[PPT];
#pragma unroll
    for (int k = 0; k < PPT; ++k) Ri[k] = Rp[is[k]];
#pragma unroll
    for (int k = 0; k < PPT; ++k) Rj[k] = Rp[js[k]];
#pragma unroll
    for (int k = 0; k < PPT; ++k)
        lj_body(Ri[k], Rj[k], eps, s2, cut2, is[k], energy, forces);
}

__global__ void lj_pairs_fb_tail_kernel(
    const v4f* __restrict__ Rp,
    const int* __restrict__ idx_i, const int* __restrict__ idx_j,
    const float* __restrict__ eps_p, const float* __restrict__ sig_p,
    const float* __restrict__ cut_p,
    float* __restrict__ energy, float* __restrict__ forces,
    int start, int n_pairs)
{
    int p = start + blockIdx.x * blockDim.x + threadIdx.x;
    if (p >= n_pairs) return;
    const float eps = eps_p[0];
    const float sig = sig_p[0];
    const float cut = cut_p[0];
    lj_body(Rp[idx_i[p]], Rp[idx_j[p]], eps, sig * sig, cut * cut,
            idx_i[p], energy, forces);
}
// -----------------------------------------------------------------------

extern "C" void kernel_launch(void* const* d_in, const int* in_sizes, int n_in,
                              void* d_out, int out_size, void* d_ws, size_t ws_size,
                              hipStream_t stream) {
    const float* R     = (const float*)d_in[0];
    const float* eps_p = (const float*)d_in[1];
    const float* sig_p = (const float*)d_in[2];
    const float* cut_p = (const float*)d_in[3];
    const int*   idx_i = (const int*)d_in[4];
    const int*   idx_j = (const int*)d_in[5];

    const int n_atoms = in_sizes[0] / 3;
    const int n_pairs = in_sizes[4];

    float* energy = (float*)d_out;
    float* forces = (float*)d_out + n_atoms;

    // d_out re-poisoned 0xAA before every timed call — zero it.
    (void)hipMemsetAsync(d_out, 0, (size_t)out_size * sizeof(float), stream);

    // ws layout: [Rp float4][packed cell table][cursor 256B][compact list]
    char* ws = (char*)d_ws;
    const size_t rp_b     = (((size_t)n_atoms * 16) + 255) & ~(size_t)255;
    const int    n_thr    = (n_atoms + 15) >> 4;
    const int    pk_words = 3 * n_thr + 1;               // +1 word read pad
    const size_t pk_b     = (((size_t)pk_words * 4) + 255) & ~(size_t)255;
    const size_t lds_b    = (((size_t)pk_words * 4) + 15) & ~(size_t)15;
    const size_t cur_b    = 256;

    const bool have_rp = ws_size >= rp_b;
    size_t fixed = rp_b + pk_b + cur_b;
    unsigned cap = 0;
    if (ws_size > fixed) {
        size_t c = (ws_size - fixed) / 8;  // bytes per v2i
        cap = (c > 0xFFFFFFFFull) ? 0xFFFFFFFFu : (unsigned)c;
    }
    const bool use_filter = have_rp && (lds_b <= 160000) && (cap >= 1u << 20);

    v4f*      Rp     = (v4f*)ws;
    unsigned* packed = (unsigned*)(ws + rp_b);
    unsigned* cursor = (unsigned*)(ws + rp_b + pk_b);
    v2i*      list   = (v2i*)(ws + fixed);

    if (have_rp) {
        int blocks = (n_atoms + 255) / 256;
        pad_R_kernel<<<blocks, 256, 0, stream>>>(R, Rp, n_atoms);
    }

    if (use_filter) {
        int cblocks = (n_thr + 255) / 256;
        cell_kernel<<<cblocks, 256, 0, stream>>>(R, packed, n_atoms);
        (void)hipMemsetAsync(cursor, 0, cur_b, stream);

        (void)hipFuncSetAttribute((const void*)filter_compact_kernel,
                                  hipFuncAttributeMaxDynamicSharedMemorySize,
                                  (int)lds_b);

        int chunk = (((n_pairs + NWG_A - 1) / NWG_A) + GRP - 1) & ~(GRP - 1);
        filter_compact_kernel<<<NWG_A, WGT, lds_b, stream>>>(
            Rp, packed, idx_i, idx_j, eps_p, sig_p, cut_p,
            list, cursor, energy, forces, n_pairs, pk_words, chunk, cap);

        lj_compact_kernel<<<NWG_B, 256, 0, stream>>>(
            Rp, list, cursor, eps_p, sig_p, cut_p, energy, forces, cap);
    } else {
        const int n_oct = n_pairs / PPT;
        const int start = n_oct * PPT;
        if (n_oct > 0) {
            int blocks = (n_oct + 255) / 256;
            lj_pairs_fb_kernel<<<blocks, 256, 0, stream>>>(
                Rp, (const v4i*)idx_i, (const v4i*)idx_j,
                eps_p, sig_p, cut_p, energy, forces, n_oct);
        }
        if (start < n_pairs) {
            lj_pairs_fb_tail_kernel<<<1, 64, 0, stream>>>(
                Rp, idx_i, idx_j, eps_p, sig_p, cut_p,
                energy, forces, start, n_pairs);
        }
    }
}

// Round 10
// 192.579 us; speedup vs baseline: 13.0227x; 1.1881x over previous
//
#include <hip/hip_runtime.h>

// LJ 12-6 over a neighbor list — round 10: fused kernel, 6x6 xy cutoff-cell
// filter. History: direct gather path walls at ~3 cyc/divergent-lane-request
// (R2 131 us). R6 fused 4x4x4 LDS filter: 91.5 us. R9 split pipeline: 113 us
// of kernels (idx read twice + list traffic) — split abandoned.
// This round, fused with: (a) 6x6 xy grid of cutoff-sized cells -> pass rate
// 19.75% vs 24.4%, cell size = runtime cutoff (clamp -> conservative pass,
// correct for ANY box/cutoff); (b) NWG=256 -> table loaded once per CU;
// (c) no ballots/syncs in the loop.

typedef int   v4i __attribute__((ext_vector_type(4)));
typedef float v4f __attribute__((ext_vector_type(4)));

#define GRP    8
#define WGT    1024
#define NWG_F  256

__global__ void __launch_bounds__(256) pad_R_kernel(
    const float* __restrict__ R, v4f* __restrict__ Rp, int n_atoms)
{
    int a = blockIdx.x * blockDim.x + threadIdx.x;
    if (a < n_atoms) {
        v4f v;
        v.x = R[3 * a + 0];
        v.y = R[3 * a + 1];
        v.z = R[3 * a + 2];
        v.w = 0.0f;
        Rp[a] = v;  // 16B aligned: single-transaction gathers
    }
}

// Pack 6-bit cell ids (cx | cy<<3, cells of size cutoff, clamped to 0..7):
// thread t owns atoms [16t,16t+16) -> 96 bits -> 3 words (no write races).
__global__ void __launch_bounds__(256) cell_kernel(
    const float* __restrict__ R, const float* __restrict__ cut_p,
    unsigned* __restrict__ packed, int n_atoms)
{
    int t = blockIdx.x * blockDim.x + threadIdx.x;
    int n_thr = (n_atoms + 15) >> 4;
    if (t >= n_thr) return;
    const float inv_cut = 1.0f / cut_p[0];
    int a0 = t << 4;
    unsigned w[3] = {0u, 0u, 0u};
#pragma unroll
    for (int k = 0; k < 16; ++k) {
        int a = a0 + k;
        unsigned c = 0u;
        if (a < n_atoms) {
            int cx = min(7, max(0, (int)(R[3 * a + 0] * inv_cut)));
            int cy = min(7, max(0, (int)(R[3 * a + 1] * inv_cut)));
            c = (unsigned)(cx | (cy << 3));
        }
        int bit = 6 * k, word = bit >> 5, off = bit & 31;
        w[word] |= c << off;
        if (off > 26) w[word + 1] |= c >> (32 - off);
    }
    packed[3 * t + 0] = w[0];
    packed[3 * t + 1] = w[1];
    packed[3 * t + 2] = w[2];
}

__device__ __forceinline__ unsigned cell6(const unsigned char* c8, unsigned a) {
    unsigned bit = a * 6u;
    unsigned by  = bit >> 3;
    unsigned v   = (unsigned)c8[by] | ((unsigned)c8[by + 1] << 8);
    return (v >> (bit & 7u)) & 63u;
}

__device__ __forceinline__ void lj_body(
    v4f A, v4f B, float eps, float s2, float cut2, int gi,
    float* __restrict__ energy, float* __restrict__ forces)
{
    const float dx = A.x - B.x, dy = A.y - B.y, dz = A.z - B.z;
    const float r2 = dx * dx + dy * dy + dz * dz;
    if (r2 < cut2 && r2 > 1e-10f) {
        const float inv  = 1.0f / r2;
        const float sr2  = s2 * inv;
        const float sr6  = sr2 * sr2 * sr2;
        const float sr12 = sr6 * sr6;
        const float e    = 2.0f * eps * (sr12 - sr6);              // 0.5 * 4eps
        const float f    = 24.0f * eps * (2.0f * sr12 - sr6) * inv;
        atomicAdd(&energy[gi], e);
        atomicAdd(&forces[3 * gi + 0], f * dx);
        atomicAdd(&forces[3 * gi + 1], f * dy);
        atomicAdd(&forces[3 * gi + 2], f * dz);
    }
}

// Fused: LDS cell filter (19.75% pass) -> masked gathers -> LJ + atomics.
// Cell size == cutoff: r < cutoff => per-dim cell diff <= 1 always (clamped
// cells only ADD passes). No pass-all fallback needed.
__global__ void __launch_bounds__(WGT) lj_fused_kernel(
    const v4f* __restrict__ Rp,
    const unsigned* __restrict__ packed,
    const int* __restrict__ idx_i,
    const int* __restrict__ idx_j,
    const float* __restrict__ eps_p,
    const float* __restrict__ sig_p,
    const float* __restrict__ cut_p,
    float* __restrict__ energy,
    float* __restrict__ forces,
    int n_pairs, int pk_words, int chunk)
{
    extern __shared__ unsigned lds[];
    for (int w = threadIdx.x; w < pk_words; w += WGT)
        lds[w] = packed[w];
    __syncthreads();
    const unsigned char* c8 = (const unsigned char*)lds;

    const float eps  = eps_p[0];
    const float sig  = sig_p[0];
    const float cut  = cut_p[0];
    const float s2   = sig * sig;
    const float cut2 = cut * cut;

    const int cs = blockIdx.x * chunk;
    const int ce = min(cs + chunk, n_pairs);

    for (int p = cs + threadIdx.x * GRP; p < ce; p += WGT * GRP) {
        int is8[GRP], js8[GRP];
        if (p + GRP <= n_pairs) {   // p % 8 == 0 -> int4-aligned fast path
            v4i a0 = __builtin_nontemporal_load((const v4i*)idx_i + (p >> 2));
            v4i a1 = __builtin_nontemporal_load((const v4i*)idx_i + (p >> 2) + 1);
            v4i b0 = __builtin_nontemporal_load((const v4i*)idx_j + (p >> 2));
            v4i b1 = __builtin_nontemporal_load((const v4i*)idx_j + (p >> 2) + 1);
            is8[0] = a0.x; is8[1] = a0.y; is8[2] = a0.z; is8[3] = a0.w;
            is8[4] = a1.x; is8[5] = a1.y; is8[6] = a1.z; is8[7] = a1.w;
            js8[0] = b0.x; js8[1] = b0.y; js8[2] = b0.z; js8[3] = b0.w;
            js8[4] = b1.x; js8[5] = b1.y; js8[6] = b1.z; js8[7] = b1.w;
        } else {
#pragma unroll
            for (int k = 0; k < GRP; ++k) {
                bool v = (p + k < n_pairs);
                is8[k] = v ? idx_i[p + k] : 0;
                js8[k] = v ? idx_j[p + k] : 0;
                // padded entries: i==j==0 -> r2==0 -> rejected by r2>1e-10
            }
        }

        // Phase 1: LDS xy-cell filter
        unsigned m = 0u;
#pragma unroll
        for (int k = 0; k < GRP; ++k) {
            unsigned ci = cell6(c8, (unsigned)is8[k]);
            unsigned cj = cell6(c8, (unsigned)js8[k]);
            int ddx = (int)(ci & 7u) - (int)(cj & 7u);
            int ddy = (int)(ci >> 3) - (int)(cj >> 3);
            bool ok = ((unsigned)(ddx + 1) <= 2u) & ((unsigned)(ddy + 1) <= 2u);
            if (ok) m |= (1u << k);
        }

        // Phase 2: exec-masked gathers — masked lanes issue NO requests
        v4f Ri[GRP], Rj[GRP];
#pragma unroll
        for (int k = 0; k < GRP; ++k)
            if (m & (1u << k)) { Ri[k] = Rp[is8[k]]; Rj[k] = Rp[js8[k]]; }

        // Phase 3: compute + sparse atomics (~1.9% true pairs)
#pragma unroll
        for (int k = 0; k < GRP; ++k)
            if (m & (1u << k))
                lj_body(Ri[k], Rj[k], eps, s2, cut2, is8[k], energy, forces);
    }
}

// ---------- fallback (R2 structure, 131 us) if ws/LDS insufficient ----------
#define PPT 8
__global__ void __launch_bounds__(256) lj_pairs_fb_kernel(
    const v4f* __restrict__ Rp,
    const v4i* __restrict__ idx_i4, const v4i* __restrict__ idx_j4,
    const float* __restrict__ eps_p, const float* __restrict__ sig_p,
    const float* __restrict__ cut_p,
    float* __restrict__ energy, float* __restrict__ forces, int n_oct)
{
    int t = blockIdx.x * blockDim.x + threadIdx.x;
    if (t >= n_oct) return;
    const float eps  = eps_p[0];
    const float sig  = sig_p[0];
    const float cut  = cut_p[0];
    const float s2   = sig * sig;
    const float cut2 = cut * cut;
    v4i ii0 = __builtin_nontemporal_load(idx_i4 + 2 * t);
    v4i ii1 = __builtin_nontemporal_load(idx_i4 + 2 * t + 1);
    v4i jj0 = __builtin_nontemporal_load(idx_j4 + 2 * t);
    v4i jj1 = __builtin_nontemporal_load(idx_j4 + 2 * t + 1);
    int is[PPT] = { ii0.x, ii0.y, ii0.z, ii0.w, ii1.x, ii1.y, ii1.z, ii1.w };
    int js[PPT] = { jj0.x, jj0.y, jj0.z, jj0.w, jj1.x, jj1.y, jj1.z, jj1.w };
    v4f Ri[PPT], Rj[PPT];
#pragma unroll
    for (int k = 0; k < PPT; ++k) Ri[k] = Rp[is[k]];
#pragma unroll
    for (int k = 0; k < PPT; ++k) Rj[k] = Rp[js[k]];
#pragma unroll
    for (int k = 0; k < PPT; ++k)
        lj_body(Ri[k], Rj[k], eps, s2, cut2, is[k], energy, forces);
}

__global__ void lj_pairs_fb_tail_kernel(
    const v4f* __restrict__ Rp,
    const int* __restrict__ idx_i, const int* __restrict__ idx_j,
    const float* __restrict__ eps_p, const float* __restrict__ sig_p,
    const float* __restrict__ cut_p,
    float* __restrict__ energy, float* __restrict__ forces,
    int start, int n_pairs)
{
    int p = start + blockIdx.x * blockDim.x + threadIdx.x;
    if (p >= n_pairs) return;
    const float eps = eps_p[0];
    const float sig = sig_p[0];
    const float cut = cut_p[0];
    lj_body(Rp[idx_i[p]], Rp[idx_j[p]], eps, sig * sig, cut * cut,
            idx_i[p], energy, forces);
}
// -----------------------------------------------------------------------------

extern "C" void kernel_launch(void* const* d_in, const int* in_sizes, int n_in,
                              void* d_out, int out_size, void* d_ws, size_t ws_size,
                              hipStream_t stream) {
    const float* R     = (const float*)d_in[0];
    const float* eps_p = (const float*)d_in[1];
    const float* sig_p = (const float*)d_in[2];
    const float* cut_p = (const float*)d_in[3];
    const int*   idx_i = (const int*)d_in[4];
    const int*   idx_j = (const int*)d_in[5];

    const int n_atoms = in_sizes[0] / 3;
    const int n_pairs = in_sizes[4];

    float* energy = (float*)d_out;
    float* forces = (float*)d_out + n_atoms;

    // d_out re-poisoned 0xAA before every timed call — zero it.
    (void)hipMemsetAsync(d_out, 0, (size_t)out_size * sizeof(float), stream);

    // ws layout: [Rp float4][packed 6-bit cell table]
    char* ws = (char*)d_ws;
    const size_t rp_b     = (((size_t)n_atoms * 16) + 255) & ~(size_t)255;
    const int    n_thr    = (n_atoms + 15) >> 4;
    const int    pk_words = 3 * n_thr + 1;               // +1 word read pad
    const size_t pk_b     = (((size_t)pk_words * 4) + 255) & ~(size_t)255;
    const size_t lds_b    = (((size_t)pk_words * 4) + 15) & ~(size_t)15;

    const bool have_rp    = ws_size >= rp_b;
    const bool use_filter = have_rp && (ws_size >= rp_b + pk_b)
                            && (lds_b <= 160000);

    v4f*      Rp     = (v4f*)ws;
    unsigned* packed = (unsigned*)(ws + rp_b);

    if (have_rp) {
        int blocks = (n_atoms + 255) / 256;
        pad_R_kernel<<<blocks, 256, 0, stream>>>(R, Rp, n_atoms);
    }

    if (use_filter) {
        int cblocks = (n_thr + 255) / 256;
        cell_kernel<<<cblocks, 256, 0, stream>>>(R, cut_p, packed, n_atoms);

        (void)hipFuncSetAttribute((const void*)lj_fused_kernel,
                                  hipFuncAttributeMaxDynamicSharedMemorySize,
                                  (int)lds_b);

        // one WG per CU: table loaded into LDS exactly once per CU
        int chunk = (((n_pairs + NWG_F - 1) / NWG_F) + GRP - 1) & ~(GRP - 1);
        lj_fused_kernel<<<NWG_F, WGT, lds_b, stream>>>(
            Rp, packed, idx_i, idx_j, eps_p, sig_p, cut_p,
            energy, forces, n_pairs, pk_words, chunk);
    } else {
        const int n_oct = n_pairs / PPT;
        const int start = n_oct * PPT;
        if (n_oct > 0) {
            int blocks = (n_oct + 255) / 256;
            lj_pairs_fb_kernel<<<blocks, 256, 0, stream>>>(
                Rp, (const v4i*)idx_i, (const v4i*)idx_j,
                eps_p, sig_p, cut_p, energy, forces, n_oct);
        }
        if (start < n_pairs) {
            lj_pairs_fb_tail_kernel<<<1, 64, 0, stream>>>(
                Rp, idx_i, idx_j, eps_p, sig_p, cut_p,
                energy, forces, start, n_pairs);
        }
    }
}